// Round 1
// baseline (3127.171 us; speedup 1.0000x reference)
//
#include <hip/hip_runtime.h>

typedef unsigned short u16;
typedef unsigned int   u32;
typedef __attribute__((ext_vector_type(4))) float f32x4;
typedef __attribute__((ext_vector_type(8))) short b16x8;

#define T_ 256
#define B_ 32
#define V_ 32000
#define H_ 256

// fp32 -> bf16 round-to-nearest-even
__device__ __forceinline__ u16 f2bf(float f){
  union { float fv; u32 uv; } v; v.fv = f;
  return (u16)((v.uv + 0x7FFFu + ((v.uv >> 16) & 1u)) >> 16);
}
__device__ __forceinline__ float sigm(float z){ return 1.0f / (1.0f + __expf(-z)); }

// ---------------------------------------------------------------------------
// prep: decW -> bf16 ; W^T bf16 copies (WhT0, WiT1, WhT1, WiT0) ; flag reset
// WT[m][j][k] = W_m[k][j]  -> MFMA B-fragment (8 consecutive k at fixed col j)
// becomes one contiguous 16B load.
// ---------------------------------------------------------------------------
__global__ __launch_bounds__(256)
void prep_kernel(const float* __restrict__ Wi, const float* __restrict__ Wh,
                 const float* __restrict__ decW,
                 u16* __restrict__ decWb, u16* __restrict__ wt,
                 u32* __restrict__ flags){
  const int NDEC = V_ * H_;          // 8,192,000
  const int NWT  = 4 * H_ * H_;      // 262,144
  const int total = NDEC + NWT + 8;
  for (int i = blockIdx.x * blockDim.x + threadIdx.x; i < total;
       i += gridDim.x * blockDim.x){
    if (i < NDEC){
      decWb[i] = f2bf(decW[i]);
    } else if (i < NDEC + NWT){
      int j = i - NDEC;
      int m = j >> 16;               // H*H = 65536 per matrix
      int r = j & 65535;
      int row = r >> 8;              // output row = source column
      int k   = r & 255;             // output col = source row
      const float* src = (m == 0) ? Wh
                       : (m == 1) ? (Wi + H_ * H_)
                       : (m == 2) ? (Wh + H_ * H_)
                       :            Wi;
      wt[j] = f2bf(src[k * H_ + row]);
    } else {
      flags[i - (NDEC + NWT)] = 0;
    }
  }
}

// ---------------------------------------------------------------------------
// x0[t*B+b][j] = bh0[j] + sum_k emb[ids[t*B+b]][k] * Wi0[k][j]
// tile: 128 rows x 64 cols per WG (512 thr, 8 waves: wave = mtile, 4 ntiles)
// ---------------------------------------------------------------------------
__global__ __launch_bounds__(512, 2)
void x0_kernel(const int* __restrict__ ids, const float* __restrict__ emb,
               const u16* __restrict__ WiT0, const float* __restrict__ bh,
               float* __restrict__ x0){
  const int tid = threadIdx.x, w = tid >> 6, l = tid & 63, lr = l & 15, lh = l >> 4;
  const int mb = blockIdx.x >> 2;   // 0..63  (row block of 128)
  const int nb = blockIdx.x & 3;    // 0..3   (col block of 64)
  const int arow = mb * 128 + w * 16 + lr;            // A-fragment row
  const int id = ids[arow];
  const float* erow = emb + (size_t)id * H_;

  f32x4 acc[4];
  #pragma unroll
  for (int nt = 0; nt < 4; ++nt){
    float b0 = bh[nb * 64 + nt * 16 + lr];            // layer-0 bias
    acc[nt] = (f32x4){b0, b0, b0, b0};
  }
  #pragma unroll
  for (int ks = 0; ks < 8; ++ks){
    const float* ap = erow + ks * 32 + lh * 8;
    f32x4 e0 = *(const f32x4*)(ap);
    f32x4 e1 = *(const f32x4*)(ap + 4);
    b16x8 a;
    #pragma unroll
    for (int i2 = 0; i2 < 4; ++i2){
      a[i2]     = (short)f2bf(e0[i2]);
      a[4 + i2] = (short)f2bf(e1[i2]);
    }
    #pragma unroll
    for (int nt = 0; nt < 4; ++nt){
      b16x8 b = *(const b16x8*)(WiT0 + (size_t)(nb * 64 + nt * 16 + lr) * H_ + ks * 32 + lh * 8);
      acc[nt] = __builtin_amdgcn_mfma_f32_16x16x32_bf16(a, b, acc[nt], 0, 0, 0);
    }
  }
  #pragma unroll
  for (int nt = 0; nt < 4; ++nt)
    #pragma unroll
    for (int rr = 0; rr < 4; ++rr)
      x0[(size_t)(mb * 128 + w * 16 + lh * 4 + rr) * H_ + nb * 64 + nt * 16 + lr] = acc[nt][rr];
}

// ---------------------------------------------------------------------------
// RNN: block 0 = layer 0, block 1 = layer 1 (pipelined, flag handshake).
// 1024 thr = 16 waves, wave w owns output cols [w*16, w*16+16).
// Weights preloaded to registers; h state in LDS (XOR-swizzled bf16 [32][256]).
// ---------------------------------------------------------------------------
__global__ __launch_bounds__(1024, 4)
void rnn_kernel(const u16* __restrict__ wt, const float* __restrict__ x0,
                const float* __restrict__ bh,
                u16* __restrict__ h0seq, u16* __restrict__ outseq,
                float* __restrict__ hidOut, u32* flags){
  __shared__ u16 hlds[B_ * H_];                       // 16 KiB
  char* ldsb = (char*)hlds;
  const int tid = threadIdx.x, w = tid >> 6, l = tid & 63, lr = l & 15, lh = l >> 4;
  const int col = w * 16 + lr;

  for (int i = tid; i < B_ * H_; i += 1024) hlds[i] = 0;   // h_init = 0

  if (blockIdx.x == 0){
    // ------------------------- layer 0 -------------------------
    b16x8 wB[8];                                     // WhT0 fragments
    #pragma unroll
    for (int ks = 0; ks < 8; ++ks)
      wB[ks] = *(const b16x8*)(wt + (size_t)col * H_ + ks * 32 + lh * 8);
    __syncthreads();

    for (int t = 0; t < T_; ++t){
      float xp[2][4];                                // x0 prefetch (has bias)
      #pragma unroll
      for (int mt = 0; mt < 2; ++mt)
        #pragma unroll
        for (int rr = 0; rr < 4; ++rr)
          xp[mt][rr] = x0[(size_t)(t * B_ + mt * 16 + lh * 4 + rr) * H_ + col];

      f32x4 acc[2];
      acc[0] = (f32x4){0.f, 0.f, 0.f, 0.f};
      acc[1] = (f32x4){0.f, 0.f, 0.f, 0.f};
      #pragma unroll
      for (int ks = 0; ks < 8; ++ks){
        #pragma unroll
        for (int mt = 0; mt < 2; ++mt){
          const int row = mt * 16 + lr;
          b16x8 a = *(const b16x8*)(ldsb + ((row * 512 + ks * 64 + lh * 16) ^ ((row & 7) << 4)));
          acc[mt] = __builtin_amdgcn_mfma_f32_16x16x32_bf16(a, wB[ks], acc[mt], 0, 0, 0);
        }
      }
      __syncthreads();                               // LDS reads done
      #pragma unroll
      for (int mt = 0; mt < 2; ++mt)
        #pragma unroll
        for (int rr = 0; rr < 4; ++rr){
          const int row = mt * 16 + lh * 4 + rr;
          float hv = sigm(acc[mt][rr] + xp[mt][rr]);
          u16 hb = f2bf(hv);
          *(u16*)(ldsb + ((row * 512 + col * 2) ^ ((row & 7) << 4))) = hb;
          h0seq[(size_t)(t * B_ + row) * H_ + col] = hb;
          if (t == T_ - 1) hidOut[row * H_ + col] = hv;
        }
      __syncthreads();                               // writes visible, vmcnt drained
      if (tid == 0){
        __threadfence();                             // L2 writeback (cross-XCD release)
        __hip_atomic_store(flags, (u32)(t + 1), __ATOMIC_RELEASE, __HIP_MEMORY_SCOPE_AGENT);
      }
    }
  } else {
    // ------------------------- layer 1 -------------------------
    const u16* WiT1 = wt + 1 * H_ * H_;
    const u16* WhT1 = wt + 2 * H_ * H_;
    b16x8 wBi[8], wBh[8];
    #pragma unroll
    for (int ks = 0; ks < 8; ++ks){
      wBi[ks] = *(const b16x8*)(WiT1 + (size_t)col * H_ + ks * 32 + lh * 8);
      wBh[ks] = *(const b16x8*)(WhT1 + (size_t)col * H_ + ks * 32 + lh * 8);
    }
    const float bb = bh[H_ + col];                   // layer-1 bias
    __syncthreads();

    for (int t = 0; t < T_; ++t){
      if (tid == 0){
        while (__hip_atomic_load(flags, __ATOMIC_RELAXED, __HIP_MEMORY_SCOPE_AGENT) < (u32)(t + 1))
          __builtin_amdgcn_s_sleep(8);
        __threadfence();                             // acquire: invalidate L1/L2
      }
      __syncthreads();

      f32x4 acc[2];
      acc[0] = (f32x4){0.f, 0.f, 0.f, 0.f};
      acc[1] = (f32x4){0.f, 0.f, 0.f, 0.f};
      // h1_{t-1} @ Wh1 (LDS)
      #pragma unroll
      for (int ks = 0; ks < 8; ++ks){
        #pragma unroll
        for (int mt = 0; mt < 2; ++mt){
          const int row = mt * 16 + lr;
          b16x8 a = *(const b16x8*)(ldsb + ((row * 512 + ks * 64 + lh * 16) ^ ((row & 7) << 4)));
          acc[mt] = __builtin_amdgcn_mfma_f32_16x16x32_bf16(a, wBh[ks], acc[mt], 0, 0, 0);
        }
      }
      // h0_t @ Wi1 (global, just produced by block 0)
      #pragma unroll
      for (int ks = 0; ks < 8; ++ks){
        #pragma unroll
        for (int mt = 0; mt < 2; ++mt){
          b16x8 a = *(const b16x8*)(h0seq + (size_t)(t * B_ + mt * 16 + lr) * H_ + ks * 32 + lh * 8);
          acc[mt] = __builtin_amdgcn_mfma_f32_16x16x32_bf16(a, wBi[ks], acc[mt], 0, 0, 0);
        }
      }
      __syncthreads();
      #pragma unroll
      for (int mt = 0; mt < 2; ++mt)
        #pragma unroll
        for (int rr = 0; rr < 4; ++rr){
          const int row = mt * 16 + lh * 4 + rr;
          float hv = sigm(acc[mt][rr] + bb);
          u16 hb = f2bf(hv);
          *(u16*)(ldsb + ((row * 512 + col * 2) ^ ((row & 7) << 4))) = hb;
          outseq[(size_t)(t * B_ + row) * H_ + col] = hb;
          if (t == T_ - 1) hidOut[B_ * H_ + row * H_ + col] = hv;
        }
      __syncthreads();
    }
  }
}

// ---------------------------------------------------------------------------
// decoder: decoded[8192][32000] = outseq @ decW^T + decB
// tile 256x64 per WG (512 thr, 8 waves: 2 mtiles x 4 ntiles each)
// decWb rows ARE B^T -> contiguous 16B B-fragments.
// ---------------------------------------------------------------------------
__global__ __launch_bounds__(512, 4)
void dec_kernel(const u16* __restrict__ outseq, const u16* __restrict__ decWb,
                const float* __restrict__ decB, float* __restrict__ out){
  const int tid = threadIdx.x, w = tid >> 6, l = tid & 63, lr = l & 15, lh = l >> 4;
  const int nb = blockIdx.x;        // 0..499 (64 vocab cols)
  const int mb = blockIdx.y;        // 0..31  (256 rows)

  f32x4 acc[2][4];
  #pragma unroll
  for (int m = 0; m < 2; ++m)
    #pragma unroll
    for (int nt = 0; nt < 4; ++nt)
      acc[m][nt] = (f32x4){0.f, 0.f, 0.f, 0.f};

  #pragma unroll
  for (int ks = 0; ks < 8; ++ks){
    b16x8 a[2];
    #pragma unroll
    for (int m = 0; m < 2; ++m)
      a[m] = *(const b16x8*)(outseq + (size_t)(mb * 256 + (2 * w + m) * 16 + lr) * H_ + ks * 32 + lh * 8);
    #pragma unroll
    for (int nt = 0; nt < 4; ++nt){
      b16x8 b = *(const b16x8*)(decWb + (size_t)(nb * 64 + nt * 16 + lr) * H_ + ks * 32 + lh * 8);
      #pragma unroll
      for (int m = 0; m < 2; ++m)
        acc[m][nt] = __builtin_amdgcn_mfma_f32_16x16x32_bf16(a[m], b, acc[m][nt], 0, 0, 0);
    }
  }
  #pragma unroll
  for (int nt = 0; nt < 4; ++nt){
    const float bias = decB[nb * 64 + nt * 16 + lr];
    #pragma unroll
    for (int m = 0; m < 2; ++m)
      #pragma unroll
      for (int rr = 0; rr < 4; ++rr)
        out[(size_t)(mb * 256 + (2 * w + m) * 16 + lh * 4 + rr) * V_ + nb * 64 + nt * 16 + lr]
            = acc[m][nt][rr] + bias;
  }
}

// ---------------------------------------------------------------------------
extern "C" void kernel_launch(void* const* d_in, const int* in_sizes, int n_in,
                              void* d_out, int out_size, void* d_ws, size_t ws_size,
                              hipStream_t stream){
  const int*   ids  = (const int*)  d_in[0];
  const float* emb  = (const float*)d_in[1];
  const float* Wi   = (const float*)d_in[2];
  const float* Wh   = (const float*)d_in[3];
  const float* bh   = (const float*)d_in[4];
  const float* decW = (const float*)d_in[5];
  const float* decB = (const float*)d_in[6];
  float* out = (float*)d_out;

  char* ws = (char*)d_ws;
  u16*  decWb  = (u16*)(ws);                                        // 16,384,000 B
  u16*  h0seq  = (u16*)(ws + 16384000);                             //  4,194,304 B
  u16*  outseq = (u16*)(ws + 16384000 + 4194304);                   //  4,194,304 B
  float* x0    = (float*)(ws + 16384000 + 2 * 4194304);             //  8,388,608 B
  u16*  wt     = (u16*)(ws + 16384000 + 2 * 4194304 + 8388608);     //    524,288 B
  u32*  flags  = (u32*)(ws + 16384000 + 2 * 4194304 + 8388608 + 524288);

  prep_kernel<<<2048, 256, 0, stream>>>(Wi, Wh, decW, decWb, wt, flags);
  x0_kernel<<<256, 512, 0, stream>>>(ids, emb, wt + 3 * H_ * H_, bh, x0);
  rnn_kernel<<<2, 1024, 0, stream>>>(wt, x0, bh, h0seq, outseq,
                                     out + (size_t)T_ * B_ * V_, flags);
  dec_kernel<<<dim3(500, 32), 512, 0, stream>>>(outseq, decWb, decB, out);
}

// Round 2
// 2392.612 us; speedup vs baseline: 1.3070x; 1.3070x over previous
//
#include <hip/hip_runtime.h>

typedef unsigned short u16;
typedef unsigned int   u32;
typedef __attribute__((ext_vector_type(4))) float f32x4;
typedef __attribute__((ext_vector_type(8))) short b16x8;

#define T_ 256
#define B_ 32
#define V_ 32000
#define H_ 256

// fp32 -> bf16 round-to-nearest-even
__device__ __forceinline__ u16 f2bf(float f){
  union { float fv; u32 uv; } v; v.fv = f;
  return (u16)((v.uv + 0x7FFFu + ((v.uv >> 16) & 1u)) >> 16);
}
__device__ __forceinline__ float sigm(float z){ return 1.0f / (1.0f + __expf(-z)); }

// ---------------------------------------------------------------------------
// prep: decW -> bf16 ; W^T bf16 copies (WhT0, WiT1, WhT1, WiT0)
// wt[m][j][k] = W_m[k][j]  (j = output col, k contiguous -> 16B B-fragments)
// ---------------------------------------------------------------------------
__global__ __launch_bounds__(256)
void prep_kernel(const float* __restrict__ Wi, const float* __restrict__ Wh,
                 const float* __restrict__ decW,
                 u16* __restrict__ decWb, u16* __restrict__ wt){
  const int NDEC = V_ * H_;          // 8,192,000
  const int NWT  = 4 * H_ * H_;      // 262,144
  const int total = NDEC + NWT;
  for (int i = blockIdx.x * blockDim.x + threadIdx.x; i < total;
       i += gridDim.x * blockDim.x){
    if (i < NDEC){
      decWb[i] = f2bf(decW[i]);
    } else {
      int j = i - NDEC;
      int m = j >> 16;               // H*H = 65536 per matrix
      int r = j & 65535;
      int row = r >> 8;              // output row = source column
      int k   = r & 255;             // output col = source row
      const float* src = (m == 0) ? Wh
                       : (m == 1) ? (Wi + H_ * H_)
                       : (m == 2) ? (Wh + H_ * H_)
                       :            Wi;
      wt[j] = f2bf(src[k * H_ + row]);
    }
  }
}

// Permuted x layout (consumer = rec_kernel thread (w,lr,lh), step t):
//   element (row = mt*16+lh*4+rr, col = w*64+nt*16+lr) of the [32][256] x-slab
//   lives at  xp[t*8192 + ((((w*4+nt)*2 + mt)*4 + lh)*16 + lr)*4 + rr]
// -> rec loads 8 f32x4; producers store 1 f32x4 per (nt) — both coalesced.

// ---------------------------------------------------------------------------
// x0[t][b][j] = bh0[j] + emb[ids[t,b]] @ Wi0   (permuted store)
// tile: 128 rows x 64 cols per WG (512 thr, 8 waves)
// ---------------------------------------------------------------------------
__global__ __launch_bounds__(512, 2)
void x0_kernel(const int* __restrict__ ids, const float* __restrict__ emb,
               const u16* __restrict__ WiT0, const float* __restrict__ bh,
               float* __restrict__ xp){
  const int tid = threadIdx.x, w = tid >> 6, l = tid & 63, lr = l & 15, lh = l >> 4;
  const int mb = blockIdx.x >> 2;   // 0..63  (row block of 128)
  const int nb = blockIdx.x & 3;    // 0..3   (col block of 64)
  const int arow = mb * 128 + w * 16 + lr;
  const int id = ids[arow];
  const float* erow = emb + (size_t)id * H_;

  f32x4 acc[4];
  #pragma unroll
  for (int nt = 0; nt < 4; ++nt){
    float b0 = bh[nb * 64 + nt * 16 + lr];
    acc[nt] = (f32x4){b0, b0, b0, b0};
  }
  #pragma unroll
  for (int ks = 0; ks < 8; ++ks){
    const float* ap = erow + ks * 32 + lh * 8;
    f32x4 e0 = *(const f32x4*)(ap);
    f32x4 e1 = *(const f32x4*)(ap + 4);
    b16x8 a;
    #pragma unroll
    for (int i2 = 0; i2 < 4; ++i2){
      a[i2]     = (short)f2bf(e0[i2]);
      a[4 + i2] = (short)f2bf(e1[i2]);
    }
    #pragma unroll
    for (int nt = 0; nt < 4; ++nt){
      b16x8 b = *(const b16x8*)(WiT0 + (size_t)(nb * 64 + nt * 16 + lr) * H_ + ks * 32 + lh * 8);
      acc[nt] = __builtin_amdgcn_mfma_f32_16x16x32_bf16(a, b, acc[nt], 0, 0, 0);
    }
  }
  const int t   = mb * 4 + (w >> 1);     // global row >> 5
  const int cmt = w & 1;
  #pragma unroll
  for (int nt = 0; nt < 4; ++nt){
    size_t idx = (size_t)t * 8192 + (size_t)(((((nb * 4 + nt) * 2 + cmt) * 4 + lh) * 16 + lr)) * 4;
    *(f32x4*)(xp + idx) = acc[nt];
  }
}

// ---------------------------------------------------------------------------
// x1[t][b][j] = bh1[j] + h0seq[t,b] @ Wi1   (permuted store, bf16 A)
// ---------------------------------------------------------------------------
__global__ __launch_bounds__(512, 2)
void x1_kernel(const u16* __restrict__ h0seq, const u16* __restrict__ WiT1,
               const float* __restrict__ bh, float* __restrict__ xp){
  const int tid = threadIdx.x, w = tid >> 6, l = tid & 63, lr = l & 15, lh = l >> 4;
  const int mb = blockIdx.x >> 2;
  const int nb = blockIdx.x & 3;

  f32x4 acc[4];
  #pragma unroll
  for (int nt = 0; nt < 4; ++nt){
    float b1 = bh[H_ + nb * 64 + nt * 16 + lr];
    acc[nt] = (f32x4){b1, b1, b1, b1};
  }
  #pragma unroll
  for (int ks = 0; ks < 8; ++ks){
    b16x8 a = *(const b16x8*)(h0seq + (size_t)(mb * 128 + w * 16 + lr) * H_ + ks * 32 + lh * 8);
    #pragma unroll
    for (int nt = 0; nt < 4; ++nt){
      b16x8 b = *(const b16x8*)(WiT1 + (size_t)(nb * 64 + nt * 16 + lr) * H_ + ks * 32 + lh * 8);
      acc[nt] = __builtin_amdgcn_mfma_f32_16x16x32_bf16(a, b, acc[nt], 0, 0, 0);
    }
  }
  const int t   = mb * 4 + (w >> 1);
  const int cmt = w & 1;
  #pragma unroll
  for (int nt = 0; nt < 4; ++nt){
    size_t idx = (size_t)t * 8192 + (size_t)(((((nb * 4 + nt) * 2 + cmt) * 4 + lh) * 16 + lr)) * 4;
    *(f32x4*)(xp + idx) = acc[nt];
  }
}

// ---------------------------------------------------------------------------
// rec: h_t = sigmoid(x_t + h_{t-1} @ Wh), 256 serial steps, ONE block.
// 4 waves; wave w owns output cols [w*64, w*64+64). Wh^T in 128 VGPRs.
// h double-buffered in XOR-swizzled LDS -> exactly 1 barrier/step.
// hseq[t-1] global store overlapped with step t's MFMA.
// ---------------------------------------------------------------------------
__global__ __launch_bounds__(256, 1)
void rec_kernel(const u16* __restrict__ whT, const float* __restrict__ xp,
                u16* __restrict__ hseq, float* __restrict__ hid){
  __shared__ u16 hbuf[2][B_ * H_];                 // 2 x 16 KiB
  const int tid = threadIdx.x, w = tid >> 6, l = tid & 63, lr = l & 15, lh = l >> 4;

  // preload Wh^T fragments: wB[nt][ks]
  b16x8 wB[4][8];
  #pragma unroll
  for (int nt = 0; nt < 4; ++nt)
    #pragma unroll
    for (int ks = 0; ks < 8; ++ks)
      wB[nt][ks] = *(const b16x8*)(whT + (size_t)(w * 64 + nt * 16 + lr) * H_ + ks * 32 + lh * 8);

  for (int i = tid; i < B_ * H_; i += 256) hbuf[0][i] = 0;   // h_init = 0
  __syncthreads();

  for (int t = 0; t < T_; ++t){
    char* rb = (char*)hbuf[t & 1];
    char* wb = (char*)hbuf[(t + 1) & 1];

    // 1. store hseq[t-1] from rb — coalesced, overlaps this step's MFMA
    if (t > 0){
      #pragma unroll
      for (int j = 0; j < 4; ++j){
        const int baddr = tid * 64 + j * 16;
        const int row = baddr >> 9;
        b16x8 v = *(const b16x8*)(rb + (baddr ^ ((row & 7) << 4)));
        *(b16x8*)(hseq + (size_t)(t - 1) * (B_ * H_) + baddr / 2) = v;
      }
    }

    // 2. x prefetch (permuted layout -> 8 coalesced dwordx4)
    f32x4 xv[2][4];
    #pragma unroll
    for (int mt = 0; mt < 2; ++mt)
      #pragma unroll
      for (int nt = 0; nt < 4; ++nt)
        xv[mt][nt] = *(const f32x4*)(xp + (size_t)t * 8192
                        + (size_t)(((((w * 4 + nt) * 2 + mt) * 4 + lh) * 16 + lr)) * 4);

    // 3. MFMA: h_prev @ Wh
    f32x4 acc[2][4];
    #pragma unroll
    for (int mt = 0; mt < 2; ++mt)
      #pragma unroll
      for (int nt = 0; nt < 4; ++nt)
        acc[mt][nt] = (f32x4){0.f, 0.f, 0.f, 0.f};
    #pragma unroll
    for (int ks = 0; ks < 8; ++ks){
      #pragma unroll
      for (int mt = 0; mt < 2; ++mt){
        const int row = mt * 16 + lr;
        b16x8 a = *(const b16x8*)(rb + ((row * 512 + ks * 64 + lh * 16) ^ ((row & 7) << 4)));
        #pragma unroll
        for (int nt = 0; nt < 4; ++nt)
          acc[mt][nt] = __builtin_amdgcn_mfma_f32_16x16x32_bf16(a, wB[nt][ks], acc[mt][nt], 0, 0, 0);
      }
    }

    // 4. sigmoid + write h_t to other LDS buffer
    #pragma unroll
    for (int mt = 0; mt < 2; ++mt)
      #pragma unroll
      for (int nt = 0; nt < 4; ++nt)
        #pragma unroll
        for (int rr = 0; rr < 4; ++rr){
          const int row = mt * 16 + lh * 4 + rr;
          const int c   = w * 64 + nt * 16 + lr;
          float hv = sigm(acc[mt][nt][rr] + xv[mt][nt][rr]);
          *(u16*)(wb + ((row * 512 + c * 2) ^ ((row & 7) << 4))) = f2bf(hv);
          if (t == T_ - 1) hid[row * H_ + c] = hv;
        }
    __syncthreads();
  }

  // epilogue: store hseq[T-1] from hbuf[0]
  {
    const char* rb = (const char*)hbuf[T_ & 1];
    #pragma unroll
    for (int j = 0; j < 4; ++j){
      const int baddr = tid * 64 + j * 16;
      const int row = baddr >> 9;
      b16x8 v = *(const b16x8*)(rb + (baddr ^ ((row & 7) << 4)));
      *(b16x8*)(hseq + (size_t)(T_ - 1) * (B_ * H_) + baddr / 2) = v;
    }
  }
}

// ---------------------------------------------------------------------------
// decoder: decoded[8192][32000] = outseq @ decW^T + decB
// ---------------------------------------------------------------------------
__global__ __launch_bounds__(512, 4)
void dec_kernel(const u16* __restrict__ outseq, const u16* __restrict__ decWb,
                const float* __restrict__ decB, float* __restrict__ out){
  const int tid = threadIdx.x, w = tid >> 6, l = tid & 63, lr = l & 15, lh = l >> 4;
  const int nb = blockIdx.x;        // 0..499 (64 vocab cols)
  const int mb = blockIdx.y;        // 0..31  (256 rows)

  f32x4 acc[2][4];
  #pragma unroll
  for (int m = 0; m < 2; ++m)
    #pragma unroll
    for (int nt = 0; nt < 4; ++nt)
      acc[m][nt] = (f32x4){0.f, 0.f, 0.f, 0.f};

  #pragma unroll
  for (int ks = 0; ks < 8; ++ks){
    b16x8 a[2];
    #pragma unroll
    for (int m = 0; m < 2; ++m)
      a[m] = *(const b16x8*)(outseq + (size_t)(mb * 256 + (2 * w + m) * 16 + lr) * H_ + ks * 32 + lh * 8);
    #pragma unroll
    for (int nt = 0; nt < 4; ++nt){
      b16x8 b = *(const b16x8*)(decWb + (size_t)(nb * 64 + nt * 16 + lr) * H_ + ks * 32 + lh * 8);
      #pragma unroll
      for (int m = 0; m < 2; ++m)
        acc[m][nt] = __builtin_amdgcn_mfma_f32_16x16x32_bf16(a[m], b, acc[m][nt], 0, 0, 0);
    }
  }
  #pragma unroll
  for (int nt = 0; nt < 4; ++nt){
    const float bias = decB[nb * 64 + nt * 16 + lr];
    #pragma unroll
    for (int m = 0; m < 2; ++m)
      #pragma unroll
      for (int rr = 0; rr < 4; ++rr)
        out[(size_t)(mb * 256 + (2 * w + m) * 16 + lh * 4 + rr) * V_ + nb * 64 + nt * 16 + lr]
            = acc[m][nt][rr] + bias;
  }
}

// ---------------------------------------------------------------------------
extern "C" void kernel_launch(void* const* d_in, const int* in_sizes, int n_in,
                              void* d_out, int out_size, void* d_ws, size_t ws_size,
                              hipStream_t stream){
  const int*   ids  = (const int*)  d_in[0];
  const float* emb  = (const float*)d_in[1];
  const float* Wi   = (const float*)d_in[2];
  const float* Wh   = (const float*)d_in[3];
  const float* bh   = (const float*)d_in[4];
  const float* decW = (const float*)d_in[5];
  const float* decB = (const float*)d_in[6];
  float* out = (float*)d_out;

  char* ws = (char*)d_ws;
  u16*  decWb  = (u16*)(ws);                       // 16,384,000 B
  u16*  wt     = (u16*)(ws + 16384000);            //    524,288 B
  u16*  h0seq  = (u16*)(ws + 16908288);            //  4,194,304 B
  u16*  outseq = (u16*)(ws + 21102592);            //  4,194,304 B
  float* xp    = (float*)(ws + 25296896);          //  8,388,608 B (shared x0/x1)

  float* hid = out + (size_t)T_ * B_ * V_;         // [L][B][H] fp32 tail of d_out

  prep_kernel<<<2048, 256, 0, stream>>>(Wi, Wh, decW, decWb, wt);
  x0_kernel<<<256, 512, 0, stream>>>(ids, emb, wt + 3 * H_ * H_, bh, xp);
  rec_kernel<<<1, 256, 0, stream>>>(wt, xp, h0seq, hid);                    // layer 0 (Wh0)
  x1_kernel<<<256, 512, 0, stream>>>(h0seq, wt + 1 * H_ * H_, bh, xp);      // x1 = h0@Wi1+bh1
  rec_kernel<<<1, 256, 0, stream>>>(wt + 2 * H_ * H_, xp, outseq, hid + B_ * H_); // layer 1 (Wh1)
  dec_kernel<<<dim3(500, 32), 512, 0, stream>>>(outseq, decWb, decB, out);
}

// Round 3
// 1367.885 us; speedup vs baseline: 2.2861x; 1.7491x over previous
//
#include <hip/hip_runtime.h>

typedef unsigned short u16;
typedef unsigned int   u32;
typedef __attribute__((ext_vector_type(4)))  float f32x4;
typedef __attribute__((ext_vector_type(16))) float f32x16;
typedef __attribute__((ext_vector_type(8)))  short b16x8;

#define T_ 256
#define B_ 32
#define V_ 32000
#define H_ 256

// fp32 -> bf16 round-to-nearest-even
__device__ __forceinline__ u16 f2bf(float f){
  union { float fv; u32 uv; } v; v.fv = f;
  return (u16)((v.uv + 0x7FFFu + ((v.uv >> 16) & 1u)) >> 16);
}

// ---------------------------------------------------------------------------
// prep: decW -> bf16 ; W^T bf16 copies (WhT0, WiT1, WhT1, WiT0)
// wt[m][j][k] = W_m[k][j]  (j = output col, k contiguous -> 16B B-fragments)
// ---------------------------------------------------------------------------
__global__ __launch_bounds__(256)
void prep_kernel(const float* __restrict__ Wi, const float* __restrict__ Wh,
                 const float* __restrict__ decW,
                 u16* __restrict__ decWb, u16* __restrict__ wt){
  const int NDEC = V_ * H_;
  const int NWT  = 4 * H_ * H_;
  const int total = NDEC + NWT;
  for (int i = blockIdx.x * blockDim.x + threadIdx.x; i < total;
       i += gridDim.x * blockDim.x){
    if (i < NDEC){
      decWb[i] = f2bf(decW[i]);
    } else {
      int j = i - NDEC;
      int m = j >> 16;
      int r = j & 65535;
      int row = r >> 8;
      int k   = r & 255;
      const float* src = (m == 0) ? Wh
                       : (m == 1) ? (Wi + H_ * H_)
                       : (m == 2) ? (Wh + H_ * H_)
                       :            Wi;
      wt[j] = f2bf(src[k * H_ + row]);
    }
  }
}

// Permuted x layout for the 32x32x16 rec consumer:
//   slab element (row = q*8 + hi*4 + r2, col) of step t lives at
//   xp[t*8192 + ((q*2+hi)*256 + col)*4 + r2]
// rec thread (col, hi) loads 4 f32x4 (q=0..3); producers store 1 f32x4/(nt).

// ---------------------------------------------------------------------------
// x0[t][b][j] = bh0[j] + emb[ids[t,b]] @ Wi0   (permuted store)
// ---------------------------------------------------------------------------
__global__ __launch_bounds__(512, 2)
void x0_kernel(const int* __restrict__ ids, const float* __restrict__ emb,
               const u16* __restrict__ WiT0, const float* __restrict__ bh,
               float* __restrict__ xp){
  const int tid = threadIdx.x, w = tid >> 6, l = tid & 63, lr = l & 15, lh = l >> 4;
  const int mb = blockIdx.x >> 2;
  const int nb = blockIdx.x & 3;
  const int arow = mb * 128 + w * 16 + lr;
  const int id = ids[arow];
  const float* erow = emb + (size_t)id * H_;

  f32x4 acc[4];
  #pragma unroll
  for (int nt = 0; nt < 4; ++nt){
    float b0 = bh[nb * 64 + nt * 16 + lr];
    acc[nt] = (f32x4){b0, b0, b0, b0};
  }
  #pragma unroll
  for (int ks = 0; ks < 8; ++ks){
    const float* ap = erow + ks * 32 + lh * 8;
    f32x4 e0 = *(const f32x4*)(ap);
    f32x4 e1 = *(const f32x4*)(ap + 4);
    b16x8 a;
    #pragma unroll
    for (int i2 = 0; i2 < 4; ++i2){
      a[i2]     = (short)f2bf(e0[i2]);
      a[4 + i2] = (short)f2bf(e1[i2]);
    }
    #pragma unroll
    for (int nt = 0; nt < 4; ++nt){
      b16x8 b = *(const b16x8*)(WiT0 + (size_t)(nb * 64 + nt * 16 + lr) * H_ + ks * 32 + lh * 8);
      acc[nt] = __builtin_amdgcn_mfma_f32_16x16x32_bf16(a, b, acc[nt], 0, 0, 0);
    }
  }
  const int t   = mb * 4 + (w >> 1);
  const int q   = (w & 1) * 2 + (lh >> 1);
  const int hi2 = lh & 1;
  #pragma unroll
  for (int nt = 0; nt < 4; ++nt){
    const int col = nb * 64 + nt * 16 + lr;
    *(f32x4*)(xp + (size_t)t * 8192 + ((q * 2 + hi2) * 256 + col) * 4) = acc[nt];
  }
}

// ---------------------------------------------------------------------------
// x1[t][b][j] = bh1[j] + h0seq[t,b] @ Wi1   (permuted store)
// ---------------------------------------------------------------------------
__global__ __launch_bounds__(512, 2)
void x1_kernel(const u16* __restrict__ h0seq, const u16* __restrict__ WiT1,
               const float* __restrict__ bh, float* __restrict__ xp){
  const int tid = threadIdx.x, w = tid >> 6, l = tid & 63, lr = l & 15, lh = l >> 4;
  const int mb = blockIdx.x >> 2;
  const int nb = blockIdx.x & 3;

  f32x4 acc[4];
  #pragma unroll
  for (int nt = 0; nt < 4; ++nt){
    float b1 = bh[H_ + nb * 64 + nt * 16 + lr];
    acc[nt] = (f32x4){b1, b1, b1, b1};
  }
  #pragma unroll
  for (int ks = 0; ks < 8; ++ks){
    b16x8 a = *(const b16x8*)(h0seq + (size_t)(mb * 128 + w * 16 + lr) * H_ + ks * 32 + lh * 8);
    #pragma unroll
    for (int nt = 0; nt < 4; ++nt){
      b16x8 b = *(const b16x8*)(WiT1 + (size_t)(nb * 64 + nt * 16 + lr) * H_ + ks * 32 + lh * 8);
      acc[nt] = __builtin_amdgcn_mfma_f32_16x16x32_bf16(a, b, acc[nt], 0, 0, 0);
    }
  }
  const int t   = mb * 4 + (w >> 1);
  const int q   = (w & 1) * 2 + (lh >> 1);
  const int hi2 = lh & 1;
  #pragma unroll
  for (int nt = 0; nt < 4; ++nt){
    const int col = nb * 64 + nt * 16 + lr;
    *(f32x4*)(xp + (size_t)t * 8192 + ((q * 2 + hi2) * 256 + col) * 4) = acc[nt];
  }
}

// ---------------------------------------------------------------------------
// rec: h_t = sigmoid(x_t + h_{t-1} @ Wh), 256 serial steps, ONE block.
// 8 waves (512 thr), 32x32x16 MFMA; wave w owns cols [w*32, w*32+32).
// Wh^T in 64 VGPR/lane. h double-buffered in XOR-swizzled LDS.
// x double-buffered in registers (prefetch t+1 during step t, unroll-2).
// LDS layout: byte(row,col) = row*512 + (col*2 ^ ((row&7)<<4))
// ---------------------------------------------------------------------------
__global__ __launch_bounds__(512, 1)
void rec_kernel(const u16* __restrict__ whT, const float* __restrict__ xp,
                u16* __restrict__ hseq, float* __restrict__ hid){
  __shared__ u16 hb[2][B_ * H_];                     // 2 x 16 KiB
  const int tid = threadIdx.x, w = tid >> 6, l = tid & 63;
  const int la = l & 31;                             // A-row / B-col lane id
  const int hi = l >> 5;                             // k-half select
  const int col = w * 32 + la;                       // output column

  // B-fragments: wB[ks] = WhT[col][ks*16 + hi*8 .. +8]
  b16x8 wB[16];
  #pragma unroll
  for (int ks = 0; ks < 16; ++ks)
    wB[ks] = *(const b16x8*)(whT + (size_t)col * H_ + ks * 16 + hi * 8);

  // A-read addresses (loop-invariant): row = la
  int ra[16];
  #pragma unroll
  for (int ks = 0; ks < 16; ++ks)
    ra[ks] = la * 512 + ((ks * 32 + hi * 16) ^ ((la & 7) << 4));

  // sigmoid-write addresses: row = q*8 + hi*4 + r2 -> row&7 = hi*4+r2
  int wa[4];
  #pragma unroll
  for (int r2 = 0; r2 < 4; ++r2)
    wa[r2] = hi * 2048 + ((col * 2) ^ ((hi * 4 + r2) << 4));

  // hseq-store read addresses (linear elem e = tid*16+j; row = tid>>4)
  const int srow = tid >> 4, scolb = (tid & 15) * 32;
  const int sa0 = srow * 512 + (scolb ^ ((srow & 7) << 4));
  const int sa1 = srow * 512 + ((scolb + 16) ^ ((srow & 7) << 4));

  // x-load thread offset
  const int xoff = hi * 1024 + col * 4;

  // zero h_{-1}
  { u32* z = (u32*)hb;
    for (int i = tid; i < 4096; i += 512) z[i] = 0; }

  f32x4 xa[4], xb[4];
  { const float* p0 = xp + xoff;
    xa[0] = *(const f32x4*)(p0);
    xa[1] = *(const f32x4*)(p0 + 2048);
    xa[2] = *(const f32x4*)(p0 + 4096);
    xa[3] = *(const f32x4*)(p0 + 6144); }
  __syncthreads();

#define STEP(BUF, T, XC, XN)                                                    \
  {                                                                             \
    const char* rb = (const char*)hb + (BUF) * 16384;                           \
    /* store h[T-1] (coalesced, overlaps MFMA) */                               \
    if ((T) > 0){                                                               \
      b16x8 v0 = *(const b16x8*)(rb + sa0);                                     \
      b16x8 v1 = *(const b16x8*)(rb + sa1);                                     \
      u16* hs = hseq + (size_t)((T) - 1) * 8192 + tid * 16;                     \
      *(b16x8*)(hs)     = v0;                                                   \
      *(b16x8*)(hs + 8) = v1;                                                   \
    }                                                                           \
    /* prefetch x for T+1 */                                                    \
    { const float* pn = xp + (size_t)(((T) < 255) ? (T) + 1 : 255) * 8192 + xoff; \
      XN[0] = *(const f32x4*)(pn);                                              \
      XN[1] = *(const f32x4*)(pn + 2048);                                       \
      XN[2] = *(const f32x4*)(pn + 4096);                                       \
      XN[3] = *(const f32x4*)(pn + 6144); }                                     \
    /* h_{T-1} @ Wh : two interleaved acc chains */                             \
    f32x16 acc0 = {}, acc1 = {};                                                \
    _Pragma("unroll")                                                           \
    for (int ks = 0; ks < 16; ks += 2){                                         \
      b16x8 a0 = *(const b16x8*)(rb + ra[ks]);                                  \
      b16x8 a1 = *(const b16x8*)(rb + ra[ks + 1]);                              \
      acc0 = __builtin_amdgcn_mfma_f32_32x32x16_bf16(a0, wB[ks],     acc0, 0, 0, 0); \
      acc1 = __builtin_amdgcn_mfma_f32_32x32x16_bf16(a1, wB[ks + 1], acc1, 0, 0, 0); \
    }                                                                           \
    /* sigmoid + write h_T into other buffer */                                 \
    { char* wb = (char*)hb + (1 - (BUF)) * 16384;                               \
      _Pragma("unroll")                                                         \
      for (int q = 0; q < 4; ++q)                                               \
        _Pragma("unroll")                                                       \
        for (int r2 = 0; r2 < 4; ++r2){                                         \
          float z = acc0[q * 4 + r2] + acc1[q * 4 + r2] + XC[q][r2];            \
          float s = __builtin_amdgcn_rcpf(                                      \
                      1.0f + __builtin_amdgcn_exp2f(z * -1.44269504f));         \
          *(u16*)(wb + q * 4096 + r2 * 512 + wa[r2]) = f2bf(s);                 \
        }                                                                       \
    }                                                                           \
    __syncthreads();                                                            \
  }

  for (int t2 = 0; t2 < 128; ++t2){
    const int t = t2 * 2;
    STEP(0, t,     xa, xb)
    STEP(1, t + 1, xb, xa)
  }
#undef STEP

  // epilogue: h[255] lives in hb[0]; store bf16 to hseq + fp32 to hid
  {
    const char* rb = (const char*)hb;
    b16x8 v0 = *(const b16x8*)(rb + sa0);
    b16x8 v1 = *(const b16x8*)(rb + sa1);
    u16* hs = hseq + (size_t)(T_ - 1) * 8192 + tid * 16;
    *(b16x8*)(hs)     = v0;
    *(b16x8*)(hs + 8) = v1;
    float* hd = hid + tid * 16;
    #pragma unroll
    for (int j = 0; j < 8; ++j){
      union { float fv; u32 uv; } c;
      c.uv = ((u32)(u16)v0[j]) << 16;  hd[j]     = c.fv;
      c.uv = ((u32)(u16)v1[j]) << 16;  hd[8 + j] = c.fv;
    }
  }
}

// ---------------------------------------------------------------------------
// decoder: decoded[8192][32000] = outseq @ decW^T + decB
// ---------------------------------------------------------------------------
__global__ __launch_bounds__(512, 4)
void dec_kernel(const u16* __restrict__ outseq, const u16* __restrict__ decWb,
                const float* __restrict__ decB, float* __restrict__ out){
  const int tid = threadIdx.x, w = tid >> 6, l = tid & 63, lr = l & 15, lh = l >> 4;
  const int nb = blockIdx.x;
  const int mb = blockIdx.y;

  f32x4 acc[2][4];
  #pragma unroll
  for (int m = 0; m < 2; ++m)
    #pragma unroll
    for (int nt = 0; nt < 4; ++nt)
      acc[m][nt] = (f32x4){0.f, 0.f, 0.f, 0.f};

  #pragma unroll
  for (int ks = 0; ks < 8; ++ks){
    b16x8 a[2];
    #pragma unroll
    for (int m = 0; m < 2; ++m)
      a[m] = *(const b16x8*)(outseq + (size_t)(mb * 256 + (2 * w + m) * 16 + lr) * H_ + ks * 32 + lh * 8);
    #pragma unroll
    for (int nt = 0; nt < 4; ++nt){
      b16x8 b = *(const b16x8*)(decWb + (size_t)(nb * 64 + nt * 16 + lr) * H_ + ks * 32 + lh * 8);
      #pragma unroll
      for (int m = 0; m < 2; ++m)
        acc[m][nt] = __builtin_amdgcn_mfma_f32_16x16x32_bf16(a[m], b, acc[m][nt], 0, 0, 0);
    }
  }
  #pragma unroll
  for (int nt = 0; nt < 4; ++nt){
    const float bias = decB[nb * 64 + nt * 16 + lr];
    #pragma unroll
    for (int m = 0; m < 2; ++m)
      #pragma unroll
      for (int rr = 0; rr < 4; ++rr)
        out[(size_t)(mb * 256 + (2 * w + m) * 16 + lh * 4 + rr) * V_ + nb * 64 + nt * 16 + lr]
            = acc[m][nt][rr] + bias;
  }
}

// ---------------------------------------------------------------------------
extern "C" void kernel_launch(void* const* d_in, const int* in_sizes, int n_in,
                              void* d_out, int out_size, void* d_ws, size_t ws_size,
                              hipStream_t stream){
  const int*   ids  = (const int*)  d_in[0];
  const float* emb  = (const float*)d_in[1];
  const float* Wi   = (const float*)d_in[2];
  const float* Wh   = (const float*)d_in[3];
  const float* bh   = (const float*)d_in[4];
  const float* decW = (const float*)d_in[5];
  const float* decB = (const float*)d_in[6];
  float* out = (float*)d_out;

  char* ws = (char*)d_ws;
  u16*  decWb  = (u16*)(ws);                       // 16,384,000 B
  u16*  wt     = (u16*)(ws + 16384000);            //    524,288 B
  u16*  h0seq  = (u16*)(ws + 16908288);            //  4,194,304 B
  u16*  outseq = (u16*)(ws + 21102592);            //  4,194,304 B
  float* xp    = (float*)(ws + 25296896);          //  8,388,608 B (shared x0/x1)

  float* hid = out + (size_t)T_ * B_ * V_;         // [L][B][H] fp32 tail of d_out

  prep_kernel<<<2048, 256, 0, stream>>>(Wi, Wh, decW, decWb, wt);
  x0_kernel<<<256, 512, 0, stream>>>(ids, emb, wt + 3 * H_ * H_, bh, xp);
  rec_kernel<<<1, 512, 0, stream>>>(wt, xp, h0seq, hid);                          // layer 0 (Wh0)
  x1_kernel<<<256, 512, 0, stream>>>(h0seq, wt + 1 * H_ * H_, bh, xp);            // x1 = h0@Wi1+bh1
  rec_kernel<<<1, 512, 0, stream>>>(wt + 2 * H_ * H_, xp, outseq, hid + B_ * H_); // layer 1 (Wh1)
  dec_kernel<<<dim3(500, 32), 512, 0, stream>>>(outseq, decWb, decB, out);
}

// Round 4
// 965.006 us; speedup vs baseline: 3.2406x; 1.4175x over previous
//
#include <hip/hip_runtime.h>

typedef unsigned short u16;
typedef unsigned int   u32;
typedef __attribute__((ext_vector_type(4)))  float f32x4;
typedef __attribute__((ext_vector_type(16))) float f32x16;
typedef __attribute__((ext_vector_type(8)))  short b16x8;

#define T_ 256
#define B_ 32
#define V_ 32000
#define H_ 256

// fp32 -> bf16 round-to-nearest-even
__device__ __forceinline__ u16 f2bf(float f){
  union { float fv; u32 uv; } v; v.fv = f;
  return (u16)((v.uv + 0x7FFFu + ((v.uv >> 16) & 1u)) >> 16);
}

// ---------------------------------------------------------------------------
// prep: decW -> bf16 ; W^T bf16 copies (WhT0, WiT1, WhT1, WiT0)
// wt[m][j][k] = W_m[k][j]  (j = output col, k contiguous -> 16B B-fragments)
// ---------------------------------------------------------------------------
__global__ __launch_bounds__(256)
void prep_kernel(const float* __restrict__ Wi, const float* __restrict__ Wh,
                 const float* __restrict__ decW,
                 u16* __restrict__ decWb, u16* __restrict__ wt){
  const int NDEC = V_ * H_;
  const int NWT  = 4 * H_ * H_;
  const int total = NDEC + NWT;
  for (int i = blockIdx.x * blockDim.x + threadIdx.x; i < total;
       i += gridDim.x * blockDim.x){
    if (i < NDEC){
      decWb[i] = f2bf(decW[i]);
    } else {
      int j = i - NDEC;
      int m = j >> 16;
      int r = j & 65535;
      int row = r >> 8;
      int k   = r & 255;
      const float* src = (m == 0) ? Wh
                       : (m == 1) ? (Wi + H_ * H_)
                       : (m == 2) ? (Wh + H_ * H_)
                       :            Wi;
      wt[j] = f2bf(src[k * H_ + row]);
    }
  }
}

// Permuted x layout for the 32x32x16 rec consumer:
//   slab element (row = q*8 + hi*4 + r2, col) of step t lives at
//   xp[t*8192 + ((q*2+hi)*256 + col)*4 + r2]

// ---------------------------------------------------------------------------
// x0[t][b][j] = bh0[j] + emb[ids[t,b]] @ Wi0   (permuted store)
// ---------------------------------------------------------------------------
__global__ __launch_bounds__(512, 2)
void x0_kernel(const int* __restrict__ ids, const float* __restrict__ emb,
               const u16* __restrict__ WiT0, const float* __restrict__ bh,
               float* __restrict__ xp){
  const int tid = threadIdx.x, w = tid >> 6, l = tid & 63, lr = l & 15, lh = l >> 4;
  const int mb = blockIdx.x >> 2;
  const int nb = blockIdx.x & 3;
  const int arow = mb * 128 + w * 16 + lr;
  const int id = ids[arow];
  const float* erow = emb + (size_t)id * H_;

  f32x4 acc[4];
  #pragma unroll
  for (int nt = 0; nt < 4; ++nt){
    float b0 = bh[nb * 64 + nt * 16 + lr];
    acc[nt] = (f32x4){b0, b0, b0, b0};
  }
  #pragma unroll
  for (int ks = 0; ks < 8; ++ks){
    const float* ap = erow + ks * 32 + lh * 8;
    f32x4 e0 = *(const f32x4*)(ap);
    f32x4 e1 = *(const f32x4*)(ap + 4);
    b16x8 a;
    #pragma unroll
    for (int i2 = 0; i2 < 4; ++i2){
      a[i2]     = (short)f2bf(e0[i2]);
      a[4 + i2] = (short)f2bf(e1[i2]);
    }
    #pragma unroll
    for (int nt = 0; nt < 4; ++nt){
      b16x8 b = *(const b16x8*)(WiT0 + (size_t)(nb * 64 + nt * 16 + lr) * H_ + ks * 32 + lh * 8);
      acc[nt] = __builtin_amdgcn_mfma_f32_16x16x32_bf16(a, b, acc[nt], 0, 0, 0);
    }
  }
  const int t   = mb * 4 + (w >> 1);
  const int q   = (w & 1) * 2 + (lh >> 1);
  const int hi2 = lh & 1;
  #pragma unroll
  for (int nt = 0; nt < 4; ++nt){
    const int col = nb * 64 + nt * 16 + lr;
    *(f32x4*)(xp + (size_t)t * 8192 + ((q * 2 + hi2) * 256 + col) * 4) = acc[nt];
  }
}

// ---------------------------------------------------------------------------
// x1[t][b][j] = bh1[j] + h0seq[t,b] @ Wi1   (permuted store)
// ---------------------------------------------------------------------------
__global__ __launch_bounds__(512, 2)
void x1_kernel(const u16* __restrict__ h0seq, const u16* __restrict__ WiT1,
               const float* __restrict__ bh, float* __restrict__ xp){
  const int tid = threadIdx.x, w = tid >> 6, l = tid & 63, lr = l & 15, lh = l >> 4;
  const int mb = blockIdx.x >> 2;
  const int nb = blockIdx.x & 3;

  f32x4 acc[4];
  #pragma unroll
  for (int nt = 0; nt < 4; ++nt){
    float b1 = bh[H_ + nb * 64 + nt * 16 + lr];
    acc[nt] = (f32x4){b1, b1, b1, b1};
  }
  #pragma unroll
  for (int ks = 0; ks < 8; ++ks){
    b16x8 a = *(const b16x8*)(h0seq + (size_t)(mb * 128 + w * 16 + lr) * H_ + ks * 32 + lh * 8);
    #pragma unroll
    for (int nt = 0; nt < 4; ++nt){
      b16x8 b = *(const b16x8*)(WiT1 + (size_t)(nb * 64 + nt * 16 + lr) * H_ + ks * 32 + lh * 8);
      acc[nt] = __builtin_amdgcn_mfma_f32_16x16x32_bf16(a, b, acc[nt], 0, 0, 0);
    }
  }
  const int t   = mb * 4 + (w >> 1);
  const int q   = (w & 1) * 2 + (lh >> 1);
  const int hi2 = lh & 1;
  #pragma unroll
  for (int nt = 0; nt < 4; ++nt){
    const int col = nb * 64 + nt * 16 + lr;
    *(f32x4*)(xp + (size_t)t * 8192 + ((q * 2 + hi2) * 256 + col) * 4) = acc[nt];
  }
}

// ---------------------------------------------------------------------------
// rec: h_t = sigmoid(x_t + h_{t-1} @ Wh), 256 serial steps, ONE block.
// (unchanged from round 3)
// ---------------------------------------------------------------------------
__global__ __launch_bounds__(512, 1)
void rec_kernel(const u16* __restrict__ whT, const float* __restrict__ xp,
                u16* __restrict__ hseq, float* __restrict__ hid){
  __shared__ u16 hb[2][B_ * H_];                     // 2 x 16 KiB
  const int tid = threadIdx.x, w = tid >> 6, l = tid & 63;
  const int la = l & 31;
  const int hi = l >> 5;
  const int col = w * 32 + la;

  b16x8 wB[16];
  #pragma unroll
  for (int ks = 0; ks < 16; ++ks)
    wB[ks] = *(const b16x8*)(whT + (size_t)col * H_ + ks * 16 + hi * 8);

  int ra[16];
  #pragma unroll
  for (int ks = 0; ks < 16; ++ks)
    ra[ks] = la * 512 + ((ks * 32 + hi * 16) ^ ((la & 7) << 4));

  int wa[4];
  #pragma unroll
  for (int r2 = 0; r2 < 4; ++r2)
    wa[r2] = hi * 2048 + ((col * 2) ^ ((hi * 4 + r2) << 4));

  const int srow = tid >> 4, scolb = (tid & 15) * 32;
  const int sa0 = srow * 512 + (scolb ^ ((srow & 7) << 4));
  const int sa1 = srow * 512 + ((scolb + 16) ^ ((srow & 7) << 4));

  const int xoff = hi * 1024 + col * 4;

  { u32* z = (u32*)hb;
    for (int i = tid; i < 4096; i += 512) z[i] = 0; }

  f32x4 xa[4], xb[4];
  { const float* p0 = xp + xoff;
    xa[0] = *(const f32x4*)(p0);
    xa[1] = *(const f32x4*)(p0 + 2048);
    xa[2] = *(const f32x4*)(p0 + 4096);
    xa[3] = *(const f32x4*)(p0 + 6144); }
  __syncthreads();

#define STEP(BUF, T, XC, XN)                                                    \
  {                                                                             \
    const char* rb = (const char*)hb + (BUF) * 16384;                           \
    if ((T) > 0){                                                               \
      b16x8 v0 = *(const b16x8*)(rb + sa0);                                     \
      b16x8 v1 = *(const b16x8*)(rb + sa1);                                     \
      u16* hs = hseq + (size_t)((T) - 1) * 8192 + tid * 16;                     \
      *(b16x8*)(hs)     = v0;                                                   \
      *(b16x8*)(hs + 8) = v1;                                                   \
    }                                                                           \
    { const float* pn = xp + (size_t)(((T) < 255) ? (T) + 1 : 255) * 8192 + xoff; \
      XN[0] = *(const f32x4*)(pn);                                              \
      XN[1] = *(const f32x4*)(pn + 2048);                                       \
      XN[2] = *(const f32x4*)(pn + 4096);                                       \
      XN[3] = *(const f32x4*)(pn + 6144); }                                     \
    f32x16 acc0 = {}, acc1 = {};                                                \
    _Pragma("unroll")                                                           \
    for (int ks = 0; ks < 16; ks += 2){                                         \
      b16x8 a0 = *(const b16x8*)(rb + ra[ks]);                                  \
      b16x8 a1 = *(const b16x8*)(rb + ra[ks + 1]);                              \
      acc0 = __builtin_amdgcn_mfma_f32_32x32x16_bf16(a0, wB[ks],     acc0, 0, 0, 0); \
      acc1 = __builtin_amdgcn_mfma_f32_32x32x16_bf16(a1, wB[ks + 1], acc1, 0, 0, 0); \
    }                                                                           \
    { char* wb = (char*)hb + (1 - (BUF)) * 16384;                               \
      _Pragma("unroll")                                                         \
      for (int q = 0; q < 4; ++q)                                               \
        _Pragma("unroll")                                                       \
        for (int r2 = 0; r2 < 4; ++r2){                                         \
          float z = acc0[q * 4 + r2] + acc1[q * 4 + r2] + XC[q][r2];            \
          float s = __builtin_amdgcn_rcpf(                                      \
                      1.0f + __builtin_amdgcn_exp2f(z * -1.44269504f));         \
          *(u16*)(wb + q * 4096 + r2 * 512 + wa[r2]) = f2bf(s);                 \
        }                                                                       \
    }                                                                           \
    __syncthreads();                                                            \
  }

  for (int t2 = 0; t2 < 128; ++t2){
    const int t = t2 * 2;
    STEP(0, t,     xa, xb)
    STEP(1, t + 1, xb, xa)
  }
#undef STEP

  {
    const char* rb = (const char*)hb;
    b16x8 v0 = *(const b16x8*)(rb + sa0);
    b16x8 v1 = *(const b16x8*)(rb + sa1);
    u16* hs = hseq + (size_t)(T_ - 1) * 8192 + tid * 16;
    *(b16x8*)(hs)     = v0;
    *(b16x8*)(hs + 8) = v1;
    float* hd = hid + tid * 16;
    #pragma unroll
    for (int j = 0; j < 8; ++j){
      union { float fv; u32 uv; } c;
      c.uv = ((u32)(u16)v0[j]) << 16;  hd[j]     = c.fv;
      c.uv = ((u32)(u16)v1[j]) << 16;  hd[8 + j] = c.fv;
    }
  }
}

// ---------------------------------------------------------------------------
// decoder: decoded[8192][32000] = outseq @ decW^T + decB
// 256x256 tile, BK=64, double-buffered LDS (128 KiB), 8 waves (2M x 4N),
// 32x32x16 MFMA. Reg-staged global->LDS with XOR chunk swizzle
// (chunk ^= row&7 within each 128 B row) -> 4-way max on ds_read_b128.
// Chunked XCD swizzle: 32 consecutive blocks (one decWb panel) per XCD chunk.
// ---------------------------------------------------------------------------
__global__ __launch_bounds__(512, 1)
void dec_kernel(const u16* __restrict__ A, const u16* __restrict__ Bw,
                const float* __restrict__ decB, float* __restrict__ out){
  __shared__ u16 sA[2][256 * 64];                   // 2 x 32 KiB
  __shared__ u16 sB[2][256 * 64];                   // 2 x 32 KiB
  const int tid = threadIdx.x, w = tid >> 6, l = tid & 63;
  const int la = l & 31, hi = l >> 5;
  const int wm = w >> 2, wn = w & 3;

  // XCD-chunked swizzle: 4000 blocks = 8 XCDs x 500; mb fastest inside chunk
  const int bid = blockIdx.x;
  const int sb  = (bid & 7) * 500 + (bid >> 3);
  const int mb  = sb & 31;                          // 0..31
  const int nb  = sb >> 5;                          // 0..124

  // staging mapping: sweep s covers rows s*64 + srow, chunk sc (16 B)
  const int srow = tid >> 3;                        // 0..63
  const int sc   = tid & 7;                         // 0..7
  const int scx  = sc ^ (srow & 7);                 // swizzled chunk
  const size_t gA = ((size_t)(mb * 256 + srow)) * H_ + sc * 8;
  const size_t gB = ((size_t)(nb * 256 + srow)) * H_ + sc * 8;
  const int    sl = srow * 128 + scx * 16;          // LDS byte offset (sweep 0)

  b16x8 rA[4], rB[4];
#define GLOADS(KK)                                                              \
  { _Pragma("unroll")                                                           \
    for (int s = 0; s < 4; ++s){                                                \
      rA[s] = *(const b16x8*)(A  + gA + (size_t)s * 64 * H_ + (KK) * 64);       \
      rB[s] = *(const b16x8*)(Bw + gB + (size_t)s * 64 * H_ + (KK) * 64);       \
    } }
#define DSWRITE(BUF)                                                            \
  { _Pragma("unroll")                                                           \
    for (int s = 0; s < 4; ++s){                                                \
      *(b16x8*)((char*)sA[BUF] + s * 8192 + sl) = rA[s];                        \
      *(b16x8*)((char*)sB[BUF] + s * 8192 + sl) = rB[s];                        \
    } }

  // fragment read offsets (within a buffer), row stride 128 B
  const int aRow = wm * 128 + la;                   // + mt*32
  const int bRow = wn * 64 + la;                    // + nt*32
  int fOff[4];
  #pragma unroll
  for (int ks = 0; ks < 4; ++ks)
    fOff[ks] = ((ks * 32 + hi * 16) ^ ((la & 7) << 4));

  f32x16 acc[4][2];
  #pragma unroll
  for (int mt = 0; mt < 4; ++mt)
    #pragma unroll
    for (int nt = 0; nt < 2; ++nt)
      acc[mt][nt] = (f32x16){};

  GLOADS(0);
  #pragma unroll
  for (int kk = 0; kk < 4; ++kk){
    DSWRITE(kk & 1);
    if (kk < 3) GLOADS(kk + 1);
    __syncthreads();
    const char* bufA = (const char*)sA[kk & 1];
    const char* bufB = (const char*)sB[kk & 1];
    #pragma unroll
    for (int ks = 0; ks < 4; ++ks){
      b16x8 aF[4], bF[2];
      #pragma unroll
      for (int mt = 0; mt < 4; ++mt)
        aF[mt] = *(const b16x8*)(bufA + (aRow + mt * 32) * 128 + fOff[ks]);
      #pragma unroll
      for (int nt = 0; nt < 2; ++nt)
        bF[nt] = *(const b16x8*)(bufB + (bRow + nt * 32) * 128 + fOff[ks]);
      #pragma unroll
      for (int mt = 0; mt < 4; ++mt)
        #pragma unroll
        for (int nt = 0; nt < 2; ++nt)
          acc[mt][nt] = __builtin_amdgcn_mfma_f32_32x32x16_bf16(aF[mt], bF[nt], acc[mt][nt], 0, 0, 0);
    }
    __syncthreads();
  }
#undef GLOADS
#undef DSWRITE

  // epilogue: bias + store (C layout: col=la, row=(r&3)+8*(r>>2)+4*hi)
  #pragma unroll
  for (int nt = 0; nt < 2; ++nt){
    const int colg = nb * 256 + wn * 64 + nt * 32 + la;
    const float bias = decB[colg];
    #pragma unroll
    for (int mt = 0; mt < 4; ++mt){
      const int rowb = mb * 256 + wm * 128 + mt * 32 + hi * 4;
      #pragma unroll
      for (int r = 0; r < 16; ++r){
        const int rowg = rowb + (r & 3) + 8 * (r >> 2);
        out[(size_t)rowg * V_ + colg] = acc[mt][nt][r] + bias;
      }
    }
  }
}

// ---------------------------------------------------------------------------
extern "C" void kernel_launch(void* const* d_in, const int* in_sizes, int n_in,
                              void* d_out, int out_size, void* d_ws, size_t ws_size,
                              hipStream_t stream){
  const int*   ids  = (const int*)  d_in[0];
  const float* emb  = (const float*)d_in[1];
  const float* Wi   = (const float*)d_in[2];
  const float* Wh   = (const float*)d_in[3];
  const float* bh   = (const float*)d_in[4];
  const float* decW = (const float*)d_in[5];
  const float* decB = (const float*)d_in[6];
  float* out = (float*)d_out;

  char* ws = (char*)d_ws;
  u16*  decWb  = (u16*)(ws);                       // 16,384,000 B
  u16*  wt     = (u16*)(ws + 16384000);            //    524,288 B
  u16*  h0seq  = (u16*)(ws + 16908288);            //  4,194,304 B
  u16*  outseq = (u16*)(ws + 21102592);            //  4,194,304 B
  float* xp    = (float*)(ws + 25296896);          //  8,388,608 B (shared x0/x1)

  float* hid = out + (size_t)T_ * B_ * V_;         // [L][B][H] fp32 tail of d_out

  prep_kernel<<<2048, 256, 0, stream>>>(Wi, Wh, decW, decWb, wt);
  x0_kernel<<<256, 512, 0, stream>>>(ids, emb, wt + 3 * H_ * H_, bh, xp);
  rec_kernel<<<1, 512, 0, stream>>>(wt, xp, h0seq, hid);                          // layer 0 (Wh0)
  x1_kernel<<<256, 512, 0, stream>>>(h0seq, wt + 1 * H_ * H_, bh, xp);            // x1 = h0@Wi1+bh1
  rec_kernel<<<1, 512, 0, stream>>>(wt + 2 * H_ * H_, xp, outseq, hid + B_ * H_); // layer 1 (Wh1)
  dec_kernel<<<4000, 512, 0, stream>>>(outseq, decWb, decB, out);
}